// Round 2
// baseline (427.478 us; speedup 1.0000x reference)
//
#include <hip/hip_runtime.h>
#include <hip/hip_cooperative_groups.h>
#include <math.h>

namespace cg = cooperative_groups;

#define HH 256
#define NN 64
#define LL 4096
#define BB 8
#define CC 8            // L-chunks per (b,h) scan unit (= waves per unit)
#define LC (LL / CC)    // 512
#define GG 16           // blocked-Horner group size
#define HN (HH * NN)    // 16384
#define GRID 512        // 2 blocks/CU on 256 CUs -- cooperative-resident

typedef __attribute__((ext_vector_type(2))) float pf2;
typedef __attribute__((ext_vector_type(16))) float f16v;
typedef const __attribute__((address_space(4))) f16v* cf16p;  // -> s_load_dwordx16

// ws layout (floats):
//   u_ws (float [B][H][L])  @ 0         (8388608 floats)
//   g    (float [B][H])     @ 8388608   (2048)
//
// Single cooperative kernel, 512 blocks x 512 threads (exactly 2 blocks/CU):
//   phase A: embedding gather + transpose  (1 tile of 64 ids per block)
//   grid.sync
//   phase B: blocked-Horner scan, 4 (b,h) units per block; per-(h,n)
//            constants (dA, w, dA^(512k)) recomputed in-register -- the
//            precompute kernel and its dA/wv/pw global round-trips are gone
//   grid.sync
//   phase C: output projection + GLU (4 h per block)
__global__ __launch_bounds__(512, 4) void fused_kernel(
    const int* __restrict__ ids, const float* __restrict__ emb,
    const float* __restrict__ log_dt, const float* __restrict__ A_log_re,
    const float* __restrict__ A_im, const float* __restrict__ B_re,
    const float* __restrict__ B_im, const float* __restrict__ C_re,
    const float* __restrict__ C_im, const float* __restrict__ Dv,
    const float* __restrict__ W, const float* __restrict__ bvec,
    float* __restrict__ u_ws, float* __restrict__ g, float* __restrict__ out) {
    __shared__ union SMem {
        struct { int ids_s[64]; float tb[2][64][65]; } a;   // gather: 33.5 KB
        float2 part[CC][NN];                                // scan reduce: 4 KB
        struct { float gs[HH]; float zb[8]; } o;            // out: 1 KB
    } sm;

    int t = threadIdx.x;
    int bid = blockIdx.x;

    // ---------------- phase A: gather + transpose ----------------
    {
        int b = bid >> 6;
        int tile = bid & 63;
        int w = t >> 6;           // wave id 0..7
        int lane = t & 63;
        int rq = lane >> 4;       // row-within-quad 0..3
        int kc = lane & 15;       // float4 column 0..15
        if (t < 64) sm.a.ids_s[t] = ids[b * LL + tile * 64 + t];
        __syncthreads();
        // prologue: chunk 0 -> buf 0 (4 rows x 64B per wave-instr)
        {
            int r0 = w * 8 + rq;
            float4 v0 = *(const float4*)(emb + (long)sm.a.ids_s[r0] * HH + 4 * kc);
            float4 v1 = *(const float4*)(emb + (long)sm.a.ids_s[r0 + 4] * HH + 4 * kc);
            sm.a.tb[0][r0][4 * kc + 0] = v0.x;
            sm.a.tb[0][r0][4 * kc + 1] = v0.y;
            sm.a.tb[0][r0][4 * kc + 2] = v0.z;
            sm.a.tb[0][r0][4 * kc + 3] = v0.w;
            sm.a.tb[0][r0 + 4][4 * kc + 0] = v1.x;
            sm.a.tb[0][r0 + 4][4 * kc + 1] = v1.y;
            sm.a.tb[0][r0 + 4][4 * kc + 2] = v1.z;
            sm.a.tb[0][r0 + 4][4 * kc + 3] = v1.w;
        }
        __syncthreads();
        #pragma unroll
        for (int c4 = 0; c4 < 4; ++c4) {
            int cur = c4 & 1;
            float4 v0, v1;
            if (c4 < 3) {   // issue next chunk's global loads early
                int r0 = w * 8 + rq;
                v0 = *(const float4*)(emb + (long)sm.a.ids_s[r0] * HH +
                                      (c4 + 1) * 64 + 4 * kc);
                v1 = *(const float4*)(emb + (long)sm.a.ids_s[r0 + 4] * HH +
                                      (c4 + 1) * 64 + 4 * kc);
            }
            // store phase for chunk c4
            #pragma unroll
            for (int it = 0; it < 2; ++it) {
                int hq = w * 8 + it * 4 + rq;   // h' in [0,64)
                int s0 = 4 * kc;                // s in [0,64) step 4
                float4 o4;
                o4.x = sm.a.tb[cur][s0 + 0][hq];
                o4.y = sm.a.tb[cur][s0 + 1][hq];
                o4.z = sm.a.tb[cur][s0 + 2][hq];
                o4.w = sm.a.tb[cur][s0 + 3][hq];
                *(float4*)(u_ws + ((long)(b * HH + c4 * 64 + hq)) * LL +
                           tile * 64 + s0) = o4;
            }
            if (c4 < 3) {   // land prefetched chunk into the other buffer
                int r0 = w * 8 + rq;
                sm.a.tb[cur ^ 1][r0][4 * kc + 0] = v0.x;
                sm.a.tb[cur ^ 1][r0][4 * kc + 1] = v0.y;
                sm.a.tb[cur ^ 1][r0][4 * kc + 2] = v0.z;
                sm.a.tb[cur ^ 1][r0][4 * kc + 3] = v0.w;
                sm.a.tb[cur ^ 1][r0 + 4][4 * kc + 0] = v1.x;
                sm.a.tb[cur ^ 1][r0 + 4][4 * kc + 1] = v1.y;
                sm.a.tb[cur ^ 1][r0 + 4][4 * kc + 2] = v1.z;
                sm.a.tb[cur ^ 1][r0 + 4][4 * kc + 3] = v1.w;
            }
            __syncthreads();
        }
    }

    __threadfence();
    cg::this_grid().sync();

    // ---------------- phase B: scan (4 units per block) ----------------
    {
        int c = __builtin_amdgcn_readfirstlane(t >> 6);   // wave id = chunk
        int n = t & 63;
        for (int iu = 0; iu < 4; ++iu) {
            int unit = bid * 4 + iu;          // = b*HH + h
            int h = unit & (HH - 1);
            int idx = h * NN + n;

            // per-(h,n) constants, recomputed in-register
            float dAre, dAim, wre, wim;
            {
                float dt = expf(log_dt[h]);
                float Are = -expf(A_log_re[idx]);
                float Aim = A_im[idx];
                float ea = expf(dt * Are);
                float sn, cs;
                sincosf(dt * Aim, &sn, &cs);
                dAre = ea * cs; dAim = ea * sn;
                float numre = dAre - 1.0f, numim = dAim;
                float den = Are * Are + Aim * Aim;
                float qre = (numre * Are + numim * Aim) / den;
                float qim = (numim * Are - numre * Aim) / den;
                float bre = B_re[idx], bim = B_im[idx];
                float dBre = bre * qre - bim * qim;
                float dBim = bre * qim + bim * qre;
                float cre = C_re[idx], cim = C_im[idx];
                wre = 2.0f * (cre * dBre - cim * dBim);
                wim = 2.0f * (cre * dBim + cim * dBre);
            }

            // Q[k] = dA^(GG-1-k); R = dA^GG
            pf2 Q[GG];
            pf2 q; q.x = 1.0f; q.y = 0.0f;
            #pragma unroll
            for (int kk = 0; kk < GG; ++kk) {
                Q[GG - 1 - kk] = q;
                pf2 nq;
                nq.x = q.x * dAre - q.y * dAim;
                nq.y = q.x * dAim + q.y * dAre;
                q = nq;
            }
            pf2 Rp; Rp.x = q.x; Rp.y = q.x;      // (Rr, Rr)
            pf2 Rm; Rm.x = -q.y; Rm.y = q.y;     // (-Ri, Ri)

            // sc = (dA^512)^(CC-1-c)  (wave-uniform exponent)
            float pr = dAre, pi = dAim;
            #pragma unroll
            for (int kk = 0; kk < 9; ++kk) {     // dA^512
                float nr = pr * pr - pi * pi;
                float ni = 2.0f * pr * pi;
                pr = nr; pi = ni;
            }
            int e = (CC - 1) - c;
            float sr = 1.0f, si = 0.0f;
            #pragma unroll
            for (int bit = 0; bit < 3; ++bit) {
                if (e & (1 << bit)) {
                    float nr = sr * pr - si * pi;
                    float ni = sr * pi + si * pr;
                    sr = nr; si = ni;
                }
                float nr = pr * pr - pi * pi;
                float ni = 2.0f * pr * pi;
                pr = nr; pi = ni;
            }

            cf16p src = (cf16p)(unsigned long long)(u_ws + (long)unit * LL + c * LC);
            pf2 P; P.x = 0.0f; P.y = 0.0f;
            #pragma unroll 4
            for (int j = 0; j < LC / GG; ++j) {  // 32 groups of 16
                f16v u = src[j];                 // one s_load_dwordx16
                pf2 T; T.x = 0.0f; T.y = 0.0f;
                #pragma unroll
                for (int kk = 0; kk < GG; ++kk) {
                    pf2 ub; ub.x = u[kk]; ub.y = u[kk];
                    T = __builtin_elementwise_fma(ub, Q[kk], T);   // v_pk_fma_f32
                }
                pf2 Ps; Ps.x = P.y; Ps.y = P.x;
                P = __builtin_elementwise_fma(P, Rp,
                        __builtin_elementwise_fma(Ps, Rm, T));
            }
            sm.part[c][n] = make_float2(P.x * sr - P.y * si,
                                        P.x * si + P.y * sr);
            __syncthreads();

            if (c == 0) {
                float Sr = 0.0f, Si = 0.0f;
                #pragma unroll
                for (int cc = 0; cc < CC; ++cc) {
                    float2 v = sm.part[cc][n];
                    Sr += v.x; Si += v.y;
                }
                float contrib = fmaf(wre, Sr, -(wim * Si));
                #pragma unroll
                for (int m = 32; m > 0; m >>= 1) contrib += __shfl_xor(contrib, m);
                if (n == 0) {
                    float y = contrib + u_ws[(long)unit * LL + LL - 1] * Dv[h];
                    float ge = 0.5f * y * (1.0f + erff(y * 0.70710678118654752f));
                    g[unit] = ge;
                }
            }
            __syncthreads();   // protect sm.part for next unit
        }
    }

    __threadfence();
    cg::this_grid().sync();

    // ---------------- phase C: out projection + GLU ----------------
    {
        int b = bid >> 6;
        int tile = bid & 63;     // 4 h per block
        int w = t >> 6, lane = t & 63;
        if (t < HH) sm.o.gs[t] = g[b * HH + t];
        __syncthreads();
        int hh = tile * 4 + (w >> 1);
        int o = (w & 1) * HH + hh;
        float4 wv4 = ((const float4*)(W + o * HH))[lane];
        float4 gv4 = ((const float4*)sm.o.gs)[lane];
        float p = wv4.x * gv4.x + wv4.y * gv4.y + wv4.z * gv4.z + wv4.w * gv4.w;
        #pragma unroll
        for (int m = 32; m > 0; m >>= 1) p += __shfl_xor(p, m);
        if (lane == 0) sm.o.zb[w] = p + bvec[o];
        __syncthreads();
        if (t < 4) {
            float z1 = sm.o.zb[2 * t + 0];
            float z2 = sm.o.zb[2 * t + 1];
            out[b * HH + tile * 4 + t] = z1 * (1.0f / (1.0f + expf(-z2)));
        }
    }
}

extern "C" void kernel_launch(void* const* d_in, const int* in_sizes, int n_in,
                              void* d_out, int out_size, void* d_ws, size_t ws_size,
                              hipStream_t stream) {
    const int* input_ids = (const int*)d_in[0];
    const float* embedding = (const float*)d_in[1];
    const float* log_dt = (const float*)d_in[2];
    const float* A_log_re = (const float*)d_in[3];
    const float* A_im = (const float*)d_in[4];
    const float* B_re = (const float*)d_in[5];
    const float* B_im = (const float*)d_in[6];
    const float* C_re = (const float*)d_in[7];
    const float* C_im = (const float*)d_in[8];
    const float* D = (const float*)d_in[9];
    const float* W_out = (const float*)d_in[10];
    const float* b_out = (const float*)d_in[11];
    float* out = (float*)d_out;

    float* ws = (float*)d_ws;
    float* u_ws = ws;                       // B*H*L floats
    float* g = ws + 8388608;                // B*H floats

    void* args[] = {
        (void*)&input_ids, (void*)&embedding, (void*)&log_dt, (void*)&A_log_re,
        (void*)&A_im, (void*)&B_re, (void*)&B_im, (void*)&C_re, (void*)&C_im,
        (void*)&D, (void*)&W_out, (void*)&b_out,
        (void*)&u_ws, (void*)&g, (void*)&out
    };
    hipLaunchCooperativeKernel((void*)fused_kernel, dim3(GRID), dim3(512),
                               args, 0, stream);
}

// Round 3
// 225.360 us; speedup vs baseline: 1.8969x; 1.8969x over previous
//
#include <hip/hip_runtime.h>
#include <math.h>

#define HH 256
#define NN 64
#define LL 4096
#define BB 8
#define CC 8            // L-chunks for parallelism (= waves per scan block)
#define LC (LL / CC)    // 512
#define GG 16           // blocked-Horner group size
#define HN (HH * NN)    // 16384
#define UNITS (BB * HH) // 2048 scan blocks
#define NFIN 64         // finisher blocks (8 per batch, 32 h each)

typedef __attribute__((ext_vector_type(2))) float pf2;
typedef __attribute__((ext_vector_type(16))) float f16v;
typedef const __attribute__((address_space(4))) f16v* cf16p;  // -> s_load_dwordx16

// ws layout (floats):
//   dA   (float2[HN])          @ 0         (32768 floats)
//   wv   (float2[HN])          @ 32768     (32768)
//   pw   (float2[CC][HN])      @ 65536     (262144)
//   u_ws (float [B][H][L])     @ 327680    (8388608)
//   g    (float [B][H])        @ 10813440  (2048)
//   ticket (int)               @ 10815488

// Fused frontend: blocks [0,512) materialize u (gather+transpose);
// blocks [512,544) do the per-(h,n) constant precompute + ticket init.
__global__ __launch_bounds__(512) void frontend_kernel(
    const int* __restrict__ ids, const float* __restrict__ emb,
    const float* __restrict__ log_dt, const float* __restrict__ A_log_re,
    const float* __restrict__ A_im, const float* __restrict__ B_re,
    const float* __restrict__ B_im, const float* __restrict__ C_re,
    const float* __restrict__ C_im,
    float2* __restrict__ dAo, float2* __restrict__ wo, float2* __restrict__ pw,
    float* __restrict__ u_ws, int* __restrict__ ticket) {
    int t = threadIdx.x;
    if (blockIdx.x < BB * 64) {
        __shared__ int ids_s[64];
        __shared__ float tb[2][64][65];   // [buf][s][h'], stride 65 ≡ 1 mod 32
        int b = blockIdx.x >> 6;
        int tile = blockIdx.x & 63;
        int w = t >> 6;           // wave id 0..7
        int lane = t & 63;
        int rq = lane >> 4;       // row-within-quad 0..3
        int k = lane & 15;        // float4 column 0..15
        if (t < 64) ids_s[t] = ids[b * LL + tile * 64 + t];
        __syncthreads();
        // prologue: chunk 0 -> buf 0. Each wave-instr loads 4 rows x 64B.
        {
            int r0 = w * 8 + rq;
            float4 v0 = *(const float4*)(emb + (long)ids_s[r0] * HH + 4 * k);
            float4 v1 = *(const float4*)(emb + (long)ids_s[r0 + 4] * HH + 4 * k);
            tb[0][r0][4 * k + 0] = v0.x;
            tb[0][r0][4 * k + 1] = v0.y;
            tb[0][r0][4 * k + 2] = v0.z;
            tb[0][r0][4 * k + 3] = v0.w;
            tb[0][r0 + 4][4 * k + 0] = v1.x;
            tb[0][r0 + 4][4 * k + 1] = v1.y;
            tb[0][r0 + 4][4 * k + 2] = v1.z;
            tb[0][r0 + 4][4 * k + 3] = v1.w;
        }
        __syncthreads();
        #pragma unroll
        for (int c4 = 0; c4 < 4; ++c4) {
            int cur = c4 & 1;
            float4 v0, v1;
            if (c4 < 3) {   // issue next chunk's global loads early
                int r0 = w * 8 + rq;
                v0 = *(const float4*)(emb + (long)ids_s[r0] * HH +
                                      (c4 + 1) * 64 + 4 * k);
                v1 = *(const float4*)(emb + (long)ids_s[r0 + 4] * HH +
                                      (c4 + 1) * 64 + 4 * k);
            }
            #pragma unroll
            for (int it = 0; it < 2; ++it) {
                int hq = w * 8 + it * 4 + rq;   // h' in [0,64)
                int s0 = 4 * k;                 // s in [0,64) step 4
                float4 o;
                o.x = tb[cur][s0 + 0][hq];
                o.y = tb[cur][s0 + 1][hq];
                o.z = tb[cur][s0 + 2][hq];
                o.w = tb[cur][s0 + 3][hq];
                *(float4*)(u_ws + ((long)(b * HH + c4 * 64 + hq)) * LL +
                           tile * 64 + s0) = o;
            }
            if (c4 < 3) {   // land prefetched chunk into the other buffer
                int r0 = w * 8 + rq;
                tb[cur ^ 1][r0][4 * k + 0] = v0.x;
                tb[cur ^ 1][r0][4 * k + 1] = v0.y;
                tb[cur ^ 1][r0][4 * k + 2] = v0.z;
                tb[cur ^ 1][r0][4 * k + 3] = v0.w;
                tb[cur ^ 1][r0 + 4][4 * k + 0] = v1.x;
                tb[cur ^ 1][r0 + 4][4 * k + 1] = v1.y;
                tb[cur ^ 1][r0 + 4][4 * k + 2] = v1.z;
                tb[cur ^ 1][r0 + 4][4 * k + 3] = v1.w;
            }
            __syncthreads();
        }
    } else {
        // ---- precompute: dA, w = 2*C0*dB, pw[k] = dA^(512k) ----
        if (blockIdx.x == BB * 64 && t == 0) *ticket = 0;   // per-iter init
        int idx = (blockIdx.x - BB * 64) * 512 + t;   // h*64+n
        int h = idx >> 6;
        float dt = expf(log_dt[h]);
        float Are = -expf(A_log_re[idx]);
        float Aim = A_im[idx];
        float ea = expf(dt * Are);
        float sn, cs;
        sincosf(dt * Aim, &sn, &cs);
        float dAre = ea * cs, dAim = ea * sn;
        float numre = dAre - 1.0f, numim = dAim;
        float den = Are * Are + Aim * Aim;
        float qre = (numre * Are + numim * Aim) / den;
        float qim = (numim * Are - numre * Aim) / den;
        float bre = B_re[idx], bim = B_im[idx];
        float dBre = bre * qre - bim * qim;
        float dBim = bre * qim + bim * qre;
        float cre = C_re[idx], cim = C_im[idx];
        dAo[idx] = make_float2(dAre, dAim);
        wo[idx] = make_float2(2.0f * (cre * dBre - cim * dBim),
                              2.0f * (cre * dBim + cim * dBre));
        float pr = dAre, pi = dAim;
        #pragma unroll
        for (int kk = 0; kk < 9; ++kk) {        // dA^512
            float nr = pr * pr - pi * pi;
            float ni = 2.0f * pr * pi;
            pr = nr; pi = ni;
        }
        float qr = 1.0f, qi = 0.0f;
        #pragma unroll
        for (int kk = 0; kk < CC; ++kk) {
            pw[kk * HN + idx] = make_float2(qr, qi);
            float nr = qr * pr - qi * pi, ni = qr * pi + qi * pr;
            qr = nr; qi = ni;
        }
    }
}

// Fused scan+combine+output: one block per (b,h), 8 waves = 8 L-chunks.
// After publishing g[bh] (agent-scope release), each block increments a
// device ticket; the LAST 64 blocks become finishers: block f does the
// (b = f>>3, h-slice = (f&7)*32) chunk of the output GEMV + GLU. Removes
// the separate out_kernel dispatch and its launch gap.
__global__ __launch_bounds__(512) void scan_kernel(
    const float* __restrict__ u_ws, const float2* __restrict__ dAv,
    const float2* __restrict__ pw, const float2* __restrict__ wv,
    const float* __restrict__ Dv, float* __restrict__ g,
    const float* __restrict__ W, const float* __restrict__ bvec,
    float* __restrict__ out, int* __restrict__ ticket) {
    __shared__ float2 part[CC][NN];   // 4 KB
    __shared__ int sm_role;
    __shared__ float sm_gs[HH];
    __shared__ float sm_zv[NFIN];
    int t = threadIdx.x;
    int c = __builtin_amdgcn_readfirstlane(t >> 6);   // wave id = chunk
    int n = t & 63;
    int bh = blockIdx.x;
    int h = bh & (HH - 1);

    float2 dA = dAv[h * NN + n];
    // Q[k] = dA^(GG-1-k) as (re,im) pairs; R = dA^GG
    pf2 Q[GG];
    pf2 q; q.x = 1.0f; q.y = 0.0f;
    #pragma unroll
    for (int k = 0; k < GG; ++k) {
        Q[GG - 1 - k] = q;
        pf2 nq;
        nq.x = q.x * dA.x - q.y * dA.y;
        nq.y = q.x * dA.y + q.y * dA.x;
        q = nq;
    }
    pf2 Rp; Rp.x = q.x; Rp.y = q.x;      // (Rr, Rr)
    pf2 Rm; Rm.x = -q.y; Rm.y = q.y;     // (-Ri, Ri)

    cf16p src = (cf16p)(unsigned long long)(u_ws + bh * LL + c * LC);
    pf2 P; P.x = 0.0f; P.y = 0.0f;
    #pragma unroll 4
    for (int j = 0; j < LC / GG; ++j) {  // 32 groups of 16
        f16v u = src[j];                 // one s_load_dwordx16
        pf2 T; T.x = 0.0f; T.y = 0.0f;
        #pragma unroll
        for (int k = 0; k < GG; ++k) {
            pf2 ub; ub.x = u[k]; ub.y = u[k];
            T = __builtin_elementwise_fma(ub, Q[k], T);   // v_pk_fma_f32
        }
        pf2 Ps; Ps.x = P.y; Ps.y = P.x;
        P = __builtin_elementwise_fma(P, Rp, __builtin_elementwise_fma(Ps, Rm, T));
    }
    // scale by dA^(512*(CC-1-c)) and stash in LDS
    float2 sc = pw[(CC - 1 - c) * HN + h * NN + n];
    part[c][n] = make_float2(P.x * sc.x - P.y * sc.y,
                             P.x * sc.y + P.y * sc.x);
    __syncthreads();

    if (c == 0) {
        float Sr = 0.0f, Si = 0.0f;
        #pragma unroll
        for (int cc = 0; cc < CC; ++cc) {
            float2 v = part[cc][n];
            Sr += v.x; Si += v.y;
        }
        float2 wc = wv[h * NN + n];
        float contrib = fmaf(wc.x, Sr, -(wc.y * Si));
        #pragma unroll
        for (int m = 32; m > 0; m >>= 1) contrib += __shfl_xor(contrib, m);
        if (n == 0) {
            float y = contrib + u_ws[bh * LL + LL - 1] * Dv[h];
            float ge = 0.5f * y * (1.0f + erff(y * 0.70710678118654752f));
            // publish g with device (cross-XCD) visibility, then take ticket
            __hip_atomic_store(&g[bh], ge, __ATOMIC_RELEASE,
                               __HIP_MEMORY_SCOPE_AGENT);
            int old = __hip_atomic_fetch_add(ticket, 1, __ATOMIC_ACQ_REL,
                                             __HIP_MEMORY_SCOPE_AGENT);
            sm_role = old - (UNITS - NFIN);   // >=0 -> finisher id
        }
    }
    __syncthreads();
    int f = sm_role;
    if (f < 0) return;

    // -------- finisher: output projection + GLU for (b, 32-h slice) --------
    if (t == 0) {
        while (__hip_atomic_load(ticket, __ATOMIC_ACQUIRE,
                                 __HIP_MEMORY_SCOPE_AGENT) < UNITS)
            __builtin_amdgcn_s_sleep(8);
    }
    __syncthreads();
    int b = f >> 3;
    int slice = (f & 7) * 32;
    if (t < HH)
        sm_gs[t] = __hip_atomic_load(&g[b * HH + t], __ATOMIC_RELAXED,
                                     __HIP_MEMORY_SCOPE_AGENT);
    __syncthreads();
    int w = t >> 6, lane = t & 63;
    #pragma unroll
    for (int p = 0; p < 8; ++p) {
        int d = p * 8 + w;                       // 0..63
        int o = (d < 32) ? (slice + d) : (HH + slice + d - 32);
        float4 wv4 = ((const float4*)(W + o * HH))[lane];
        float4 gv4 = ((const float4*)sm_gs)[lane];
        float pp = wv4.x * gv4.x + wv4.y * gv4.y + wv4.z * gv4.z + wv4.w * gv4.w;
        #pragma unroll
        for (int m = 32; m > 0; m >>= 1) pp += __shfl_xor(pp, m);
        if (lane == 0) sm_zv[d] = pp + bvec[o];
    }
    __syncthreads();
    if (t < 32) {
        float z1 = sm_zv[t];
        float z2 = sm_zv[t + 32];
        out[b * HH + slice + t] = z1 * (1.0f / (1.0f + expf(-z2)));
    }
}

extern "C" void kernel_launch(void* const* d_in, const int* in_sizes, int n_in,
                              void* d_out, int out_size, void* d_ws, size_t ws_size,
                              hipStream_t stream) {
    const int* input_ids = (const int*)d_in[0];
    const float* embedding = (const float*)d_in[1];
    const float* log_dt = (const float*)d_in[2];
    const float* A_log_re = (const float*)d_in[3];
    const float* A_im = (const float*)d_in[4];
    const float* B_re = (const float*)d_in[5];
    const float* B_im = (const float*)d_in[6];
    const float* C_re = (const float*)d_in[7];
    const float* C_im = (const float*)d_in[8];
    const float* D = (const float*)d_in[9];
    const float* W_out = (const float*)d_in[10];
    const float* b_out = (const float*)d_in[11];
    float* out = (float*)d_out;

    float* ws = (float*)d_ws;
    float2* dAv = (float2*)ws;                    // HN float2
    float2* wv = (float2*)(ws + 32768);           // HN float2
    float2* pw = (float2*)(ws + 65536);           // CC*HN float2
    float* u_ws = ws + 327680;                    // B*H*L floats
    float* g = ws + 10813440;                     // B*H floats
    int* ticket = (int*)(ws + 10815488);

    frontend_kernel<<<BB * 64 + HN / 512, 512, 0, stream>>>(
        input_ids, embedding, log_dt, A_log_re, A_im, B_re, B_im, C_re, C_im,
        dAv, wv, pw, u_ws, ticket);

    scan_kernel<<<UNITS, 512, 0, stream>>>(u_ws, dAv, pw, wv, D, g,
                                           W_out, b_out, out, ticket);
}

// Round 4
// 133.771 us; speedup vs baseline: 3.1956x; 1.6847x over previous
//
#include <hip/hip_runtime.h>
#include <math.h>

#define HH 256
#define NN 64
#define LL 4096
#define BB 8
#define CC 8            // L-chunks for parallelism (= waves per scan block)
#define LC (LL / CC)    // 512
#define GG 16           // blocked-Horner group size
#define HN (HH * NN)    // 16384

typedef __attribute__((ext_vector_type(2))) float pf2;

// ws layout (floats):
//   dA   (float2[HN])          @ 0         (32768 floats)
//   wv   (float2[HN])          @ 32768     (32768)
//   pw   (float2[CC][HN])      @ 65536     (262144)
//   u_ws (float [B][H][L])     @ 327680    (8388608)
//   g    (float [B][H])        @ 10813440  (2048)

// Fused frontend: blocks [0,512) materialize u (gather+transpose);
// blocks [512,544) do the per-(h,n) constant precompute.
__global__ __launch_bounds__(512) void frontend_kernel(
    const int* __restrict__ ids, const float* __restrict__ emb,
    const float* __restrict__ log_dt, const float* __restrict__ A_log_re,
    const float* __restrict__ A_im, const float* __restrict__ B_re,
    const float* __restrict__ B_im, const float* __restrict__ C_re,
    const float* __restrict__ C_im,
    float2* __restrict__ dAo, float2* __restrict__ wo, float2* __restrict__ pw,
    float* __restrict__ u_ws) {
    int t = threadIdx.x;
    if (blockIdx.x < BB * 64) {
        __shared__ int ids_s[64];
        __shared__ float tb[2][64][65];   // [buf][s][h'], stride 65 ≡ 1 mod 32
        int b = blockIdx.x >> 6;
        int tile = blockIdx.x & 63;
        int w = t >> 6;           // wave id 0..7
        int lane = t & 63;
        int rq = lane >> 4;       // row-within-quad 0..3
        int k = lane & 15;        // float4 column 0..15
        if (t < 64) ids_s[t] = ids[b * LL + tile * 64 + t];
        __syncthreads();
        // prologue: chunk 0 -> buf 0. Each wave-instr loads 4 rows x 64B.
        {
            int r0 = w * 8 + rq;
            float4 v0 = *(const float4*)(emb + (long)ids_s[r0] * HH + 4 * k);
            float4 v1 = *(const float4*)(emb + (long)ids_s[r0 + 4] * HH + 4 * k);
            tb[0][r0][4 * k + 0] = v0.x;
            tb[0][r0][4 * k + 1] = v0.y;
            tb[0][r0][4 * k + 2] = v0.z;
            tb[0][r0][4 * k + 3] = v0.w;
            tb[0][r0 + 4][4 * k + 0] = v1.x;
            tb[0][r0 + 4][4 * k + 1] = v1.y;
            tb[0][r0 + 4][4 * k + 2] = v1.z;
            tb[0][r0 + 4][4 * k + 3] = v1.w;
        }
        __syncthreads();
        #pragma unroll
        for (int c4 = 0; c4 < 4; ++c4) {
            int cur = c4 & 1;
            float4 v0, v1;
            if (c4 < 3) {   // issue next chunk's global loads early
                int r0 = w * 8 + rq;
                v0 = *(const float4*)(emb + (long)ids_s[r0] * HH +
                                      (c4 + 1) * 64 + 4 * k);
                v1 = *(const float4*)(emb + (long)ids_s[r0 + 4] * HH +
                                      (c4 + 1) * 64 + 4 * k);
            }
            #pragma unroll
            for (int it = 0; it < 2; ++it) {
                int hq = w * 8 + it * 4 + rq;   // h' in [0,64)
                int s0 = 4 * k;                 // s in [0,64) step 4
                float4 o;
                o.x = tb[cur][s0 + 0][hq];
                o.y = tb[cur][s0 + 1][hq];
                o.z = tb[cur][s0 + 2][hq];
                o.w = tb[cur][s0 + 3][hq];
                *(float4*)(u_ws + ((long)(b * HH + c4 * 64 + hq)) * LL +
                           tile * 64 + s0) = o;
            }
            if (c4 < 3) {   // land prefetched chunk into the other buffer
                int r0 = w * 8 + rq;
                tb[cur ^ 1][r0][4 * k + 0] = v0.x;
                tb[cur ^ 1][r0][4 * k + 1] = v0.y;
                tb[cur ^ 1][r0][4 * k + 2] = v0.z;
                tb[cur ^ 1][r0][4 * k + 3] = v0.w;
                tb[cur ^ 1][r0 + 4][4 * k + 0] = v1.x;
                tb[cur ^ 1][r0 + 4][4 * k + 1] = v1.y;
                tb[cur ^ 1][r0 + 4][4 * k + 2] = v1.z;
                tb[cur ^ 1][r0 + 4][4 * k + 3] = v1.w;
            }
            __syncthreads();
        }
    } else {
        // ---- precompute: dA, w = 2*C0*dB, pw[k] = dA^(512k) ----
        int idx = (blockIdx.x - BB * 64) * 512 + t;   // h*64+n
        int h = idx >> 6;
        float dt = expf(log_dt[h]);
        float Are = -expf(A_log_re[idx]);
        float Aim = A_im[idx];
        float ea = expf(dt * Are);
        float sn, cs;
        sincosf(dt * Aim, &sn, &cs);
        float dAre = ea * cs, dAim = ea * sn;
        float numre = dAre - 1.0f, numim = dAim;
        float den = Are * Are + Aim * Aim;
        float qre = (numre * Are + numim * Aim) / den;
        float qim = (numim * Are - numre * Aim) / den;
        float bre = B_re[idx], bim = B_im[idx];
        float dBre = bre * qre - bim * qim;
        float dBim = bre * qim + bim * qre;
        float cre = C_re[idx], cim = C_im[idx];
        dAo[idx] = make_float2(dAre, dAim);
        wo[idx] = make_float2(2.0f * (cre * dBre - cim * dBim),
                              2.0f * (cre * dBim + cim * dBre));
        float pr = dAre, pi = dAim;
        #pragma unroll
        for (int kk = 0; kk < 9; ++kk) {        // dA^512
            float nr = pr * pr - pi * pi;
            float ni = 2.0f * pr * pi;
            pr = nr; pi = ni;
        }
        float qr = 1.0f, qi = 0.0f;
        #pragma unroll
        for (int kk = 0; kk < CC; ++kk) {
            pw[kk * HN + idx] = make_float2(qr, qi);
            float nr = qr * pr - qi * pi, ni = qr * pi + qi * pr;
            qr = nr; qi = ni;
        }
    }
}

// Fused scan+combine: one block per (b,h), 8 waves = 8 L-chunks. u-delivery
// via VMEM->LDS (global_load_lds, 2x1KB per wave, per-wave vmcnt(0), no
// barrier) + wave-uniform ds_read_b128 broadcasts -- replaces the
// latency-bound s_load_dwordx16 SMEM path. grid = B*H = 2048, block = 512.
__global__ __launch_bounds__(512) void scan_kernel(
    const float* __restrict__ u_ws, const float2* __restrict__ dAv,
    const float2* __restrict__ pw, const float2* __restrict__ wv,
    const float* __restrict__ Dv, float* __restrict__ g) {
    __shared__ float ub[CC][LC];      // 16 KB: per-wave u chunk
    __shared__ float2 part[CC][NN];   // 4 KB
    int t = threadIdx.x;
    int c = __builtin_amdgcn_readfirstlane(t >> 6);   // wave id = chunk
    int n = t & 63;
    int bh = blockIdx.x;
    int h = bh & (HH - 1);

    // async-stage this wave's 512-float chunk: LDS dst = uniform base +
    // lane*16B (linear), global src = base + lane*16B (coalesced 1KB/instr)
    {
        const float* src = u_ws + (long)bh * LL + c * LC + n * 4;
        __builtin_amdgcn_global_load_lds(
            (const __attribute__((address_space(1))) void*)(src),
            (__attribute__((address_space(3))) void*)(&ub[c][0]), 16, 0, 0);
        __builtin_amdgcn_global_load_lds(
            (const __attribute__((address_space(1))) void*)(src + 256),
            (__attribute__((address_space(3))) void*)(&ub[c][256]), 16, 0, 0);
    }

    float2 dA = dAv[h * NN + n];
    // Q[k] = dA^(GG-1-k) as (re,im) pairs; R = dA^GG
    pf2 Q[GG];
    pf2 q; q.x = 1.0f; q.y = 0.0f;
    #pragma unroll
    for (int k = 0; k < GG; ++k) {
        Q[GG - 1 - k] = q;
        pf2 nq;
        nq.x = q.x * dA.x - q.y * dA.y;
        nq.y = q.x * dA.y + q.y * dA.x;
        q = nq;
    }
    pf2 Rp; Rp.x = q.x; Rp.y = q.x;      // (Rr, Rr)
    pf2 Rm; Rm.x = -q.y; Rm.y = q.y;     // (-Ri, Ri)
    float2 sc = pw[(CC - 1 - c) * HN + h * NN + n];

    // wait for own staged chunk (per-wave; dA/pw loads drain too -- needed)
    asm volatile("s_waitcnt vmcnt(0)" ::: "memory");
    __builtin_amdgcn_sched_barrier(0);

    pf2 P; P.x = 0.0f; P.y = 0.0f;
    #pragma unroll 4
    for (int j = 0; j < LC / GG; ++j) {  // 32 groups of 16
        const float4* up = (const float4*)&ub[c][j * GG];  // uniform addr
        float4 u0 = up[0];               // ds_read_b128 broadcast
        float4 u1 = up[1];
        float4 u2 = up[2];
        float4 u3 = up[3];
        pf2 T; T.x = 0.0f; T.y = 0.0f;
        #define HSTEP(val, kk) { pf2 ubv; ubv.x = (val); ubv.y = (val); \
            T = __builtin_elementwise_fma(ubv, Q[kk], T); }
        HSTEP(u0.x, 0)  HSTEP(u0.y, 1)  HSTEP(u0.z, 2)  HSTEP(u0.w, 3)
        HSTEP(u1.x, 4)  HSTEP(u1.y, 5)  HSTEP(u1.z, 6)  HSTEP(u1.w, 7)
        HSTEP(u2.x, 8)  HSTEP(u2.y, 9)  HSTEP(u2.z, 10) HSTEP(u2.w, 11)
        HSTEP(u3.x, 12) HSTEP(u3.y, 13) HSTEP(u3.z, 14) HSTEP(u3.w, 15)
        #undef HSTEP
        // P = P*R + T (complex): 2 pk_fma + swap
        pf2 Ps; Ps.x = P.y; Ps.y = P.x;
        P = __builtin_elementwise_fma(P, Rp, __builtin_elementwise_fma(Ps, Rm, T));
    }
    // scale by dA^(512*(CC-1-c)) and stash in LDS
    part[c][n] = make_float2(P.x * sc.x - P.y * sc.y,
                             P.x * sc.y + P.y * sc.x);
    __syncthreads();

    if (c == 0) {
        float Sr = 0.0f, Si = 0.0f;
        #pragma unroll
        for (int cc = 0; cc < CC; ++cc) {
            float2 v = part[cc][n];
            Sr += v.x; Si += v.y;
        }
        float2 wc = wv[h * NN + n];
        float contrib = fmaf(wc.x, Sr, -(wc.y * Si));
        #pragma unroll
        for (int m = 32; m > 0; m >>= 1) contrib += __shfl_xor(contrib, m);
        if (n == 0) {
            float y = contrib + ub[CC - 1][LC - 1] * Dv[h];   // u[L-1] from LDS
            float ge = 0.5f * y * (1.0f + erff(y * 0.70710678118654752f));
            g[bh] = ge;
        }
    }
}

// Output projection + GLU. grid = B*128 (2 h per block), block = 256 (4 waves).
__global__ __launch_bounds__(256) void out_kernel(
    const float* __restrict__ g, const float* __restrict__ W,
    const float* __restrict__ bvec, float* __restrict__ out) {
    int b = blockIdx.x >> 7;
    int tile = blockIdx.x & 127;
    int t = threadIdx.x;
    int w = t >> 6, lane = t & 63;
    __shared__ float gs[HH];
    __shared__ float zb[4];
    gs[t] = g[b * HH + t];
    __syncthreads();
    int hh = tile * 2 + (w >> 1);
    int o = (w & 1) * HH + hh;
    float4 wv4 = ((const float4*)(W + o * HH))[lane];
    float4 gv4 = ((const float4*)gs)[lane];
    float p = wv4.x * gv4.x + wv4.y * gv4.y + wv4.z * gv4.z + wv4.w * gv4.w;
    #pragma unroll
    for (int m = 32; m > 0; m >>= 1) p += __shfl_xor(p, m);
    if (lane == 0) zb[w] = p + bvec[o];
    __syncthreads();
    if (t < 2) {
        int hq = tile * 2 + t;
        float z1 = zb[t * 2 + 0];
        float z2 = zb[t * 2 + 1];
        out[b * HH + hq] = z1 * (1.0f / (1.0f + expf(-z2)));
    }
}

extern "C" void kernel_launch(void* const* d_in, const int* in_sizes, int n_in,
                              void* d_out, int out_size, void* d_ws, size_t ws_size,
                              hipStream_t stream) {
    const int* input_ids = (const int*)d_in[0];
    const float* embedding = (const float*)d_in[1];
    const float* log_dt = (const float*)d_in[2];
    const float* A_log_re = (const float*)d_in[3];
    const float* A_im = (const float*)d_in[4];
    const float* B_re = (const float*)d_in[5];
    const float* B_im = (const float*)d_in[6];
    const float* C_re = (const float*)d_in[7];
    const float* C_im = (const float*)d_in[8];
    const float* D = (const float*)d_in[9];
    const float* W_out = (const float*)d_in[10];
    const float* b_out = (const float*)d_in[11];
    float* out = (float*)d_out;

    float* ws = (float*)d_ws;
    float2* dAv = (float2*)ws;                    // HN float2
    float2* wv = (float2*)(ws + 32768);           // HN float2
    float2* pw = (float2*)(ws + 65536);           // CC*HN float2
    float* u_ws = ws + 327680;                    // B*H*L floats
    float* g = ws + 10813440;                     // B*H floats

    frontend_kernel<<<BB * 64 + HN / 512, 512, 0, stream>>>(
        input_ids, embedding, log_dt, A_log_re, A_im, B_re, B_im, C_re, C_im,
        dAv, wv, pw, u_ws);

    scan_kernel<<<BB * HH, 512, 0, stream>>>(u_ws, dAv, pw, wv, D, g);

    out_kernel<<<BB * 128, 256, 0, stream>>>(g, W_out, b_out, out);
}